// Round 1
// baseline (873.676 us; speedup 1.0000x reference)
//
#include <hip/hip_runtime.h>
#include <math.h>

#define IN_DIM 128
#define NH 8
#define OC 16
#define HC 128   // NH*OC
#define CHUNK 128

// ---------------- K1: x = feature@w_lin, res(->d_out) = feature@w_res ----
// One weight column per thread held in 128 VGPRs; 4 nodes per iteration via
// LDS-broadcast float4 of transposed feature rows.
__global__ __launch_bounds__(256) void k1_gemm(const float* __restrict__ feature,
                                               const float* __restrict__ w_lin,
                                               const float* __restrict__ w_res,
                                               float* __restrict__ x,
                                               float* __restrict__ res,
                                               int N) {
  const int t = threadIdx.x;
  const float* __restrict__ W = (t < HC) ? w_lin : w_res;
  const int col = t & (HC - 1);
  float w[IN_DIM];
#pragma unroll
  for (int k = 0; k < IN_DIM; ++k) w[k] = W[k * HC + col];
  __shared__ float ft[IN_DIM * 4];
  for (int nb = blockIdx.x * 4; nb < N; nb += gridDim.x * 4) {
    __syncthreads();
    {
      const int kk = t & 127;
      const int r0 = t >> 7;
#pragma unroll
      for (int p = 0; p < 2; ++p) {
        const int row = r0 + 2 * p;
        const int n = nb + row;
        ft[kk * 4 + row] = (n < N) ? feature[(size_t)n * IN_DIM + kk] : 0.f;
      }
    }
    __syncthreads();
    float a0 = 0.f, a1 = 0.f, a2 = 0.f, a3 = 0.f;
#pragma unroll
    for (int k = 0; k < IN_DIM; ++k) {
      const float4 f = *(const float4*)&ft[k * 4];
      const float wv = w[k];
      a0 = fmaf(f.x, wv, a0);
      a1 = fmaf(f.y, wv, a1);
      a2 = fmaf(f.z, wv, a2);
      a3 = fmaf(f.w, wv, a3);
    }
    float* __restrict__ dst = (t < HC) ? x : res;
    if (nb + 0 < N) dst[(size_t)(nb + 0) * HC + col] = a0;
    if (nb + 1 < N) dst[(size_t)(nb + 1) * HC + col] = a1;
    if (nb + 2 < N) dst[(size_t)(nb + 2) * HC + col] = a2;
    if (nb + 3 < N) dst[(size_t)(nb + 3) * HC + col] = a3;
  }
}

// ---------------- K1b: al[n,h] = <x[n,h,:], att_l[h,:]>, ar likewise ------
__global__ __launch_bounds__(256) void k1b_attn(const float* __restrict__ x,
                                                const float* __restrict__ att_l,
                                                const float* __restrict__ att_r,
                                                float* __restrict__ al,
                                                float* __restrict__ ar,
                                                int N) {
  const int idx = blockIdx.x * 256 + threadIdx.x;
  if (idx >= N * NH) return;
  const int h = idx & (NH - 1);
  const float4* xp = (const float4*)(x + (size_t)idx * OC);  // idx*16 == n*128 + h*16
  const float4* lp = (const float4*)(att_l + h * OC);
  const float4* rp = (const float4*)(att_r + h * OC);
  float sl = 0.f, sr = 0.f;
#pragma unroll
  for (int q = 0; q < 4; ++q) {
    const float4 xv = xp[q], lv = lp[q], rv = rp[q];
    sl += xv.x * lv.x + xv.y * lv.y + xv.z * lv.z + xv.w * lv.w;
    sr += xv.x * rv.x + xv.y * rv.y + xv.z * rv.z + xv.w * rv.w;
  }
  al[idx] = sl;
  ar[idx] = sr;
}

// ---------------- K2: histogram of edge destinations ---------------------
__global__ __launch_bounds__(256) void k2_count(const int* __restrict__ edst,
                                                int* __restrict__ count, int E) {
  const int e = blockIdx.x * 256 + threadIdx.x;
  if (e < E) atomicAdd(&count[edst[e]], 1);
}

// ---------------- K3: exclusive scan -> row_start + cursor ---------------
__global__ __launch_bounds__(1024) void k3_scan(const int* __restrict__ count,
                                                int* __restrict__ row_start,
                                                int* __restrict__ cursor, int N) {
  __shared__ int s[1024];
  const int t = threadIdx.x;
  const int CH = (N + 1023) / 1024;
  int lo = t * CH;
  if (lo > N) lo = N;
  int hi = lo + CH;
  if (hi > N) hi = N;
  int sum = 0;
  for (int i = lo; i < hi; ++i) sum += count[i];
  s[t] = sum;
  __syncthreads();
  for (int off = 1; off < 1024; off <<= 1) {
    const int add = (t >= off) ? s[t - off] : 0;
    __syncthreads();
    s[t] += add;
    __syncthreads();
  }
  int run = s[t] - sum;  // exclusive prefix
  for (int i = lo; i < hi; ++i) {
    row_start[i] = run;
    cursor[i] = run;
    run += count[i];
  }
  if (t == 1023) row_start[N] = s[1023];
}

// ---------------- K4: per-edge logits, scatter into CSR buckets ----------
__global__ __launch_bounds__(256) void k4_scatter(const int* __restrict__ esrc,
                                                  const int* __restrict__ edst,
                                                  const float* __restrict__ ew,
                                                  const float* __restrict__ al,
                                                  const float* __restrict__ ar,
                                                  int* __restrict__ cursor,
                                                  int* __restrict__ srcs,
                                                  float* __restrict__ alpha, int E) {
  const int e = blockIdx.x * 256 + threadIdx.x;
  if (e >= E) return;
  const int sN = esrc[e], dN = edst[e];
  const float w = ew[e];
  const float4* lp = (const float4*)(al + (size_t)sN * NH);
  const float4* rp = (const float4*)(ar + (size_t)dN * NH);
  const float4 l0 = lp[0], l1 = lp[1], r0 = rp[0], r1 = rp[1];
  const int pos = atomicAdd(&cursor[dN], 1);
  float4 o0, o1;
  float v;
  v = w * (l0.x + r0.x); o0.x = (v > 0.f) ? v : 0.2f * v;
  v = w * (l0.y + r0.y); o0.y = (v > 0.f) ? v : 0.2f * v;
  v = w * (l0.z + r0.z); o0.z = (v > 0.f) ? v : 0.2f * v;
  v = w * (l0.w + r0.w); o0.w = (v > 0.f) ? v : 0.2f * v;
  v = w * (l1.x + r1.x); o1.x = (v > 0.f) ? v : 0.2f * v;
  v = w * (l1.y + r1.y); o1.y = (v > 0.f) ? v : 0.2f * v;
  v = w * (l1.z + r1.z); o1.z = (v > 0.f) ? v : 0.2f * v;
  v = w * (l1.w + r1.w); o1.w = (v > 0.f) ? v : 0.2f * v;
  srcs[pos] = sN;
  float4* op = (float4*)(alpha + (size_t)pos * NH);
  op[0] = o0;
  op[1] = o1;
}

// ---------------- K5: per-node softmax + gather-accumulate + elu + res ---
// Block = 128 threads = one dst node. Mapping A (i=t/8, h=t%8) for edge-wise
// work; mapping B (h=t/16, c=t%16) for feature-wise work. No float atomics:
// accumulate e*x[src] and scale by 1/denom at the end (normalization is
// linear).
__global__ __launch_bounds__(128) void k5_agg(const float* __restrict__ x,
                                              const float* __restrict__ alpha,
                                              const int* __restrict__ srcs,
                                              const int* __restrict__ row_start,
                                              float* __restrict__ out, int N) {
  const int n = blockIdx.x;
  const int t = threadIdx.x;
  const int s0 = row_start[n];
  const int En = row_start[n + 1] - s0;
  __shared__ float red[128];
  __shared__ float mx[NH];
  __shared__ float inv8[NH];
  __shared__ float ebuf[CHUNK * NH];
  __shared__ int sbuf[CHUNK];
  const int h_a = t & 7, i_a = t >> 3;

  // phase 1: per-head max over this node's edges (coalesced contiguous read)
  float lm = -INFINITY;
  for (int i = i_a; i < En; i += 16) lm = fmaxf(lm, alpha[(size_t)(s0 + i) * NH + h_a]);
  red[t] = lm;
  __syncthreads();
  if (t < NH) {
    float m = red[t];
    for (int j = 1; j < 16; ++j) m = fmaxf(m, red[j * NH + t]);
    mx[t] = m;
  }
  __syncthreads();

  // phase 2+3 fused, chunked: e into LDS, denom partials, gather-accumulate
  const int h_b = t >> 4, c = t & 15;
  float dpart = 0.f, facc = 0.f;
  for (int base = 0; base < En; base += CHUNK) {
    const int cnt = min(CHUNK, En - base);
    for (int i = i_a; i < cnt; i += 16) {
      const float av = alpha[(size_t)(s0 + base + i) * NH + h_a];
      const float e = __expf(av - mx[h_a]);
      ebuf[i * NH + h_a] = e;
      dpart += e;
    }
    for (int i = t; i < cnt; i += 128) sbuf[i] = srcs[s0 + base + i];
    __syncthreads();
    for (int i = 0; i < cnt; ++i) {
      facc = fmaf(ebuf[i * NH + h_b], x[(size_t)sbuf[i] * HC + h_b * OC + c], facc);
    }
    __syncthreads();
  }

  // reduce denom per head
  red[t] = dpart;
  __syncthreads();
  if (t < NH) {
    float sden = 0.f;
    for (int j = 0; j < 16; ++j) sden += red[j * NH + t];
    inv8[t] = 1.f / sden;
  }
  __syncthreads();

  const float feat = (En > 0) ? facc * inv8[h_b] : 0.f;
  const float o = (feat > 0.f) ? feat : (__expf(feat) - 1.f);  // elu
  out[(size_t)n * HC + t] += o;  // out already holds the residual from k1
}

extern "C" void kernel_launch(void* const* d_in, const int* in_sizes, int n_in,
                              void* d_out, int out_size, void* d_ws, size_t ws_size,
                              hipStream_t stream) {
  const float* feature = (const float*)d_in[0];
  const int* esrc = (const int*)d_in[1];
  const int* edst = (const int*)d_in[2];
  const float* ew = (const float*)d_in[3];
  const float* w_lin = (const float*)d_in[4];
  const float* att_l = (const float*)d_in[5];
  const float* att_r = (const float*)d_in[6];
  const float* w_res = (const float*)d_in[7];
  float* out = (float*)d_out;

  const int N = in_sizes[0] / IN_DIM;
  const int E = in_sizes[1];

  char* ws = (char*)d_ws;
  size_t off = 0;
  auto alloc = [&](size_t bytes) {
    void* p = ws + off;
    off = (off + bytes + 255) & ~(size_t)255;
    return p;
  };
  float* x = (float*)alloc((size_t)N * HC * sizeof(float));        // 25.6 MB
  float* al = (float*)alloc((size_t)N * NH * sizeof(float));       // 1.6 MB
  float* ar = (float*)alloc((size_t)N * NH * sizeof(float));       // 1.6 MB
  int* count = (int*)alloc((size_t)N * sizeof(int));               // 0.2 MB
  int* row_start = (int*)alloc((size_t)(N + 1) * sizeof(int));     // 0.2 MB
  int* cursor = (int*)alloc((size_t)N * sizeof(int));              // 0.2 MB
  int* srcs = (int*)alloc((size_t)E * sizeof(int));                // 6.4 MB
  float* alpha = (float*)alloc((size_t)E * NH * sizeof(float));    // 51.2 MB

  hipMemsetAsync(count, 0, (size_t)N * sizeof(int), stream);
  k1_gemm<<<256, 256, 0, stream>>>(feature, w_lin, w_res, x, out, N);
  k1b_attn<<<(N * NH + 255) / 256, 256, 0, stream>>>(x, att_l, att_r, al, ar, N);
  k2_count<<<(E + 255) / 256, 256, 0, stream>>>(edst, count, E);
  k3_scan<<<1, 1024, 0, stream>>>(count, row_start, cursor, N);
  k4_scatter<<<(E + 255) / 256, 256, 0, stream>>>(esrc, edst, ew, al, ar, cursor, srcs, alpha, E);
  k5_agg<<<N, 128, 0, stream>>>(x, alpha, srcs, row_start, out, N);
}

// Round 2
// 559.708 us; speedup vs baseline: 1.5610x; 1.5610x over previous
//
#include <hip/hip_runtime.h>
#include <math.h>

#define IN_DIM 128
#define NH 8
#define OC 16
#define HC 128   // NH*OC
#define CHUNK 128
#define BSTR 136 // padded bf16 stride for LDS B tiles: 272B row => 16B-aligned b128 reads,
                 // bank start 4c%32 -> 2-way aliasing (free per m136)

typedef __attribute__((ext_vector_type(8))) short short8;
typedef __attribute__((ext_vector_type(4))) float f32x4;

__device__ __forceinline__ unsigned short bf16_rne(float f) {
  unsigned int u = __builtin_bit_cast(unsigned int, f);
  u += 0x7FFFu + ((u >> 16) & 1u);
  return (unsigned short)(u >> 16);
}
__device__ __forceinline__ float bf16_to_f(unsigned short h) {
  unsigned int u = ((unsigned int)h) << 16;
  return __builtin_bit_cast(float, u);
}

// ---------------- K1: x = feature@w_lin, res(->d_out) = feature@w_res ----
// MFMA split-bf16 (A = Ah+Al, B = Bh+Bl; D = AhBh + AhBl + AlBh, rel err ~2^-15).
// B^T (both weight mats, 256 cols) staged once/block into LDS as hi/lo bf16.
// Each wave owns a 16-row strip; A frags loaded directly from global.
__global__ __launch_bounds__(256) void k1_mfma(const float* __restrict__ feature,
                                               const float* __restrict__ w_lin,
                                               const float* __restrict__ w_res,
                                               float* __restrict__ x,
                                               float* __restrict__ res,
                                               int N) {
  __shared__ unsigned short Bhi[256 * BSTR];  // 69.6 KB
  __shared__ unsigned short Blo[256 * BSTR];  // 69.6 KB
  const int t = threadIdx.x;

  // ---- stage B^T: col c = t, k contiguous, split hi/lo ----
  {
    const int c = t;
    const float* __restrict__ Wp = (c < HC) ? (w_lin + c) : (w_res + (c - HC));
    for (int k0 = 0; k0 < IN_DIM; k0 += 4) {
      unsigned short h[4], l[4];
#pragma unroll
      for (int j = 0; j < 4; ++j) {
        const float f = Wp[(size_t)(k0 + j) * HC];
        h[j] = bf16_rne(f);
        l[j] = bf16_rne(f - bf16_to_f(h[j]));
      }
      *(ushort4*)&Bhi[c * BSTR + k0] = make_ushort4(h[0], h[1], h[2], h[3]);
      *(ushort4*)&Blo[c * BSTR + k0] = make_ushort4(l[0], l[1], l[2], l[3]);
    }
  }
  __syncthreads();

  const int wave = t >> 6, lane = t & 63;
  const int n16 = lane & 15;   // col within 16-tile / A row within strip
  const int quad = lane >> 4;  // 0..3
  const int nStrips = (N + 15) >> 4;

  for (int strip = blockIdx.x * 4 + wave; strip < nStrips; strip += gridDim.x * 4) {
    const int row0 = strip * 16;
    const int arow = row0 + n16;
    const float* __restrict__ ap =
        feature + (size_t)((arow < N) ? arow : 0) * IN_DIM + quad * 8;

    short8 ahi[4], alo[4];
#pragma unroll
    for (int ks = 0; ks < 4; ++ks) {
      const float4 f0 = *(const float4*)(ap + ks * 32);
      const float4 f1 = *(const float4*)(ap + ks * 32 + 4);
      const float fv[8] = {f0.x, f0.y, f0.z, f0.w, f1.x, f1.y, f1.z, f1.w};
      short8 h, l;
#pragma unroll
      for (int j = 0; j < 8; ++j) {
        const unsigned short hh = bf16_rne(fv[j]);
        h[j] = (short)hh;
        l[j] = (short)bf16_rne(fv[j] - bf16_to_f(hh));
      }
      ahi[ks] = h;
      alo[ks] = l;
    }

#pragma unroll
    for (int cg = 0; cg < 4; ++cg) {
      f32x4 acc[4] = {{0.f, 0.f, 0.f, 0.f},
                      {0.f, 0.f, 0.f, 0.f},
                      {0.f, 0.f, 0.f, 0.f},
                      {0.f, 0.f, 0.f, 0.f}};
#pragma unroll
      for (int ks = 0; ks < 4; ++ks) {
#pragma unroll
        for (int j = 0; j < 4; ++j) {  // 4 independent acc chains hide MFMA latency
          const int boff = ((cg * 4 + j) * 16 + n16) * BSTR + ks * 32 + quad * 8;
          const short8 bh = *(const short8*)&Bhi[boff];
          const short8 bl = *(const short8*)&Blo[boff];
          acc[j] = __builtin_amdgcn_mfma_f32_16x16x32_bf16(ahi[ks], bh, acc[j], 0, 0, 0);
          acc[j] = __builtin_amdgcn_mfma_f32_16x16x32_bf16(ahi[ks], bl, acc[j], 0, 0, 0);
          acc[j] = __builtin_amdgcn_mfma_f32_16x16x32_bf16(alo[ks], bh, acc[j], 0, 0, 0);
        }
      }
#pragma unroll
      for (int j = 0; j < 4; ++j) {
        const int ct = cg * 4 + j;
        float* __restrict__ dp = (ct < 8) ? x : res;
        const int colo = (ct & 7) * 16 + n16;
#pragma unroll
        for (int r = 0; r < 4; ++r) {
          const int rr = row0 + quad * 4 + r;
          if (rr < N) dp[(size_t)rr * HC + colo] = acc[j][r];
        }
      }
    }
  }
}

// ---------------- K1b: al[n,h] = <x[n,h,:], att_l[h,:]>, ar likewise ------
__global__ __launch_bounds__(256) void k1b_attn(const float* __restrict__ x,
                                                const float* __restrict__ att_l,
                                                const float* __restrict__ att_r,
                                                float* __restrict__ al,
                                                float* __restrict__ ar,
                                                int N) {
  const int idx = blockIdx.x * 256 + threadIdx.x;
  if (idx >= N * NH) return;
  const int h = idx & (NH - 1);
  const float4* xp = (const float4*)(x + (size_t)idx * OC);  // idx*16 == n*128 + h*16
  const float4* lp = (const float4*)(att_l + h * OC);
  const float4* rp = (const float4*)(att_r + h * OC);
  float sl = 0.f, sr = 0.f;
#pragma unroll
  for (int q = 0; q < 4; ++q) {
    const float4 xv = xp[q], lv = lp[q], rv = rp[q];
    sl += xv.x * lv.x + xv.y * lv.y + xv.z * lv.z + xv.w * lv.w;
    sr += xv.x * rv.x + xv.y * rv.y + xv.z * rv.z + xv.w * rv.w;
  }
  al[idx] = sl;
  ar[idx] = sr;
}

// ---------------- K2: histogram of edge destinations ---------------------
__global__ __launch_bounds__(256) void k2_count(const int* __restrict__ edst,
                                                int* __restrict__ count, int E) {
  const int e = blockIdx.x * 256 + threadIdx.x;
  if (e < E) atomicAdd(&count[edst[e]], 1);
}

// ---------------- K3: exclusive scan -> row_start + cursor ---------------
__global__ __launch_bounds__(1024) void k3_scan(const int* __restrict__ count,
                                                int* __restrict__ row_start,
                                                int* __restrict__ cursor, int N) {
  __shared__ int s[1024];
  const int t = threadIdx.x;
  const int CH = (N + 1023) / 1024;
  int lo = t * CH;
  if (lo > N) lo = N;
  int hi = lo + CH;
  if (hi > N) hi = N;
  int sum = 0;
  for (int i = lo; i < hi; ++i) sum += count[i];
  s[t] = sum;
  __syncthreads();
  for (int off = 1; off < 1024; off <<= 1) {
    const int add = (t >= off) ? s[t - off] : 0;
    __syncthreads();
    s[t] += add;
    __syncthreads();
  }
  int run = s[t] - sum;  // exclusive prefix
  for (int i = lo; i < hi; ++i) {
    row_start[i] = run;
    cursor[i] = run;
    run += count[i];
  }
  if (t == 1023) row_start[N] = s[1023];
}

// ---------------- K4: per-edge logits, scatter into CSR buckets ----------
__global__ __launch_bounds__(256) void k4_scatter(const int* __restrict__ esrc,
                                                  const int* __restrict__ edst,
                                                  const float* __restrict__ ew,
                                                  const float* __restrict__ al,
                                                  const float* __restrict__ ar,
                                                  int* __restrict__ cursor,
                                                  int* __restrict__ srcs,
                                                  float* __restrict__ alpha, int E) {
  const int e = blockIdx.x * 256 + threadIdx.x;
  if (e >= E) return;
  const int sN = esrc[e], dN = edst[e];
  const float w = ew[e];
  const float4* lp = (const float4*)(al + (size_t)sN * NH);
  const float4* rp = (const float4*)(ar + (size_t)dN * NH);
  const float4 l0 = lp[0], l1 = lp[1], r0 = rp[0], r1 = rp[1];
  const int pos = atomicAdd(&cursor[dN], 1);
  float4 o0, o1;
  float v;
  v = w * (l0.x + r0.x); o0.x = (v > 0.f) ? v : 0.2f * v;
  v = w * (l0.y + r0.y); o0.y = (v > 0.f) ? v : 0.2f * v;
  v = w * (l0.z + r0.z); o0.z = (v > 0.f) ? v : 0.2f * v;
  v = w * (l0.w + r0.w); o0.w = (v > 0.f) ? v : 0.2f * v;
  v = w * (l1.x + r1.x); o1.x = (v > 0.f) ? v : 0.2f * v;
  v = w * (l1.y + r1.y); o1.y = (v > 0.f) ? v : 0.2f * v;
  v = w * (l1.z + r1.z); o1.z = (v > 0.f) ? v : 0.2f * v;
  v = w * (l1.w + r1.w); o1.w = (v > 0.f) ? v : 0.2f * v;
  srcs[pos] = sN;
  float4* op = (float4*)(alpha + (size_t)pos * NH);
  op[0] = o0;
  op[1] = o1;
}

// ---------------- K5: per-node softmax + gather-accumulate + elu + res ---
__global__ __launch_bounds__(128) void k5_agg(const float* __restrict__ x,
                                              const float* __restrict__ alpha,
                                              const int* __restrict__ srcs,
                                              const int* __restrict__ row_start,
                                              float* __restrict__ out, int N) {
  const int n = blockIdx.x;
  const int t = threadIdx.x;
  const int s0 = row_start[n];
  const int En = row_start[n + 1] - s0;
  __shared__ float red[128];
  __shared__ float mx[NH];
  __shared__ float inv8[NH];
  __shared__ float ebuf[CHUNK * NH];
  __shared__ int sbuf[CHUNK];
  const int h_a = t & 7, i_a = t >> 3;

  float lm = -INFINITY;
  for (int i = i_a; i < En; i += 16) lm = fmaxf(lm, alpha[(size_t)(s0 + i) * NH + h_a]);
  red[t] = lm;
  __syncthreads();
  if (t < NH) {
    float m = red[t];
    for (int j = 1; j < 16; ++j) m = fmaxf(m, red[j * NH + t]);
    mx[t] = m;
  }
  __syncthreads();

  const int h_b = t >> 4, c = t & 15;
  float dpart = 0.f, facc = 0.f;
  for (int base = 0; base < En; base += CHUNK) {
    const int cnt = min(CHUNK, En - base);
    for (int i = i_a; i < cnt; i += 16) {
      const float av = alpha[(size_t)(s0 + base + i) * NH + h_a];
      const float e = __expf(av - mx[h_a]);
      ebuf[i * NH + h_a] = e;
      dpart += e;
    }
    for (int i = t; i < cnt; i += 128) sbuf[i] = srcs[s0 + base + i];
    __syncthreads();
    for (int i = 0; i < cnt; ++i) {
      facc = fmaf(ebuf[i * NH + h_b], x[(size_t)sbuf[i] * HC + h_b * OC + c], facc);
    }
    __syncthreads();
  }

  red[t] = dpart;
  __syncthreads();
  if (t < NH) {
    float sden = 0.f;
    for (int j = 0; j < 16; ++j) sden += red[j * NH + t];
    inv8[t] = 1.f / sden;
  }
  __syncthreads();

  const float feat = (En > 0) ? facc * inv8[h_b] : 0.f;
  const float o = (feat > 0.f) ? feat : (__expf(feat) - 1.f);  // elu
  out[(size_t)n * HC + t] += o;  // out already holds the residual from k1
}

extern "C" void kernel_launch(void* const* d_in, const int* in_sizes, int n_in,
                              void* d_out, int out_size, void* d_ws, size_t ws_size,
                              hipStream_t stream) {
  const float* feature = (const float*)d_in[0];
  const int* esrc = (const int*)d_in[1];
  const int* edst = (const int*)d_in[2];
  const float* ew = (const float*)d_in[3];
  const float* w_lin = (const float*)d_in[4];
  const float* att_l = (const float*)d_in[5];
  const float* att_r = (const float*)d_in[6];
  const float* w_res = (const float*)d_in[7];
  float* out = (float*)d_out;

  const int N = in_sizes[0] / IN_DIM;
  const int E = in_sizes[1];

  char* ws = (char*)d_ws;
  size_t off = 0;
  auto alloc = [&](size_t bytes) {
    void* p = ws + off;
    off = (off + bytes + 255) & ~(size_t)255;
    return p;
  };
  float* x = (float*)alloc((size_t)N * HC * sizeof(float));
  float* al = (float*)alloc((size_t)N * NH * sizeof(float));
  float* ar = (float*)alloc((size_t)N * NH * sizeof(float));
  int* count = (int*)alloc((size_t)N * sizeof(int));
  int* row_start = (int*)alloc((size_t)(N + 1) * sizeof(int));
  int* cursor = (int*)alloc((size_t)N * sizeof(int));
  int* srcs = (int*)alloc((size_t)E * sizeof(int));
  float* alpha = (float*)alloc((size_t)E * NH * sizeof(float));

  hipMemsetAsync(count, 0, (size_t)N * sizeof(int), stream);
  k1_mfma<<<256, 256, 0, stream>>>(feature, w_lin, w_res, x, out, N);
  k1b_attn<<<(N * NH + 255) / 256, 256, 0, stream>>>(x, att_l, att_r, al, ar, N);
  k2_count<<<(E + 255) / 256, 256, 0, stream>>>(edst, count, E);
  k3_scan<<<1, 1024, 0, stream>>>(count, row_start, cursor, N);
  k4_scatter<<<(E + 255) / 256, 256, 0, stream>>>(esrc, edst, ew, al, ar, cursor, srcs, alpha, E);
  k5_agg<<<N, 128, 0, stream>>>(x, alpha, srcs, row_start, out, N);
}